// Round 8
// baseline (1316.918 us; speedup 1.0000x reference)
//
#include <hip/hip_runtime.h>

#define BATCH 32
#define H 1024
#define W 1024
#define NPIX (H * W)       // 1048576 per sample
#define ITERS 10
#define SPB 8              // strips (blocks) per image
#define NBLK (BATCH * SPB) // 256 blocks = 1 per CU (co-resident: NBLK <= #CUs)
#define BROWS (H / SPB)    // 128 rows per block
#define WROWS (BROWS / 4)  // 32 rows per wave (one wave = full 1024-px row span)
#define PX 16              // px per lane per row

typedef _Float16 half8_t __attribute__((ext_vector_type(8)));

// Per-(iteration, batch) reduction state.
struct Stats {
    unsigned maxbits[ITERS][BATCH];  // fp32 bits; values >= 0 so uint order == float order
    unsigned minbits[ITERS][BATCH];
    double   sum[ITERS][BATCH];
};

__global__ void init_all(Stats* st, unsigned* bar) {
    int i = blockIdx.x * blockDim.x + threadIdx.x;
    if (i < ITERS * BATCH) {
        (&st->maxbits[0][0])[i] = 0u;           // erosion >= 0 everywhere
        (&st->minbits[0][0])[i] = 0x7f800000u;  // +inf
        (&st->sum[0][0])[i]     = 0.0;
    }
    if (i == 0) *bar = 0u;                      // grid-barrier epoch counter
}

// halo layout: [parity][b][s][side][W] raw fp16; side 0 = strip top row, 1 = bottom row
__device__ __forceinline__ size_t halo_off(int parity, int b, int s, int side) {
    return ((((size_t)parity * BATCH + b) * SPB + s) * 2 + side) * W;
}

struct Raw { float4 p[4]; int4 t[4]; };

__device__ __forceinline__ void load_raw(const float* __restrict__ pred,
                                         const int* __restrict__ tgt,
                                         size_t off, Raw& r) {
    #pragma unroll
    for (int q = 0; q < 4; ++q) {
        r.p[q] = *(const float4*)(pred + off + 4 * q);
        r.t[q] = *(const int4*)(tgt + off + 4 * q);
    }
}

__device__ __forceinline__ void bound_from(const Raw& r, float f[PX], bool inb) {
    if (!inb) {
        #pragma unroll
        for (int j = 0; j < PX; ++j) f[j] = 0.f;
        return;
    }
    #pragma unroll
    for (int q = 0; q < 4; ++q) {
        float d;
        d = r.p[q].x - (r.t[q].x == 0 ? 1.f : 0.f); f[4 * q + 0] = d * d;
        d = r.p[q].y - (r.t[q].y == 0 ? 1.f : 0.f); f[4 * q + 1] = d * d;
        d = r.p[q].z - (r.t[q].z == 0 ? 1.f : 0.f); f[4 * q + 2] = d * d;
        d = r.p[q].w - (r.t[q].w == 0 ? 1.f : 0.f); f[4 * q + 3] = d * d;
    }
}

__device__ __forceinline__ void norm_pair(float f[PX], half8_t a, half8_t b,
                                          float emin, float invd) {
    #pragma unroll
    for (int j = 0; j < 8; ++j) {
        f[j]     = ((float)a[j] - emin) * invd;
        f[j + 8] = ((float)b[j] - emin) * invd;
    }
}

// Epoch-based grid barrier (R6-proven). Counter reset by init_all each launch.
__device__ __forceinline__ void grid_barrier(unsigned* bar, int epoch) {
    __threadfence();
    __syncthreads();
    if (threadIdx.x == 0) {
        atomicAdd(bar, 1u);
        unsigned tgt = (unsigned)NBLK * (unsigned)(epoch + 1);
        while (__hip_atomic_load(bar, __ATOMIC_RELAXED, __HIP_MEMORY_SCOPE_AGENT) < tgt) {
            __builtin_amdgcn_s_sleep(2);
        }
    }
    __syncthreads();
    __threadfence();
}

// Persistent kernel: the raw erosion field lives in VGPRs (64 x half8 = 256
// VGPRs per thread) across all 10 iterations. Iterations 1..9 are pure
// VALU + shuffles; only boundary rows travel through LDS (wave seams) and a
// small parity-double-buffered global halo (block seams).
__global__ __launch_bounds__(256, 1) void erode_persist(
    const float* __restrict__ pred, const int* __restrict__ target,
    _Float16* __restrict__ halo, Stats* __restrict__ st, unsigned* __restrict__ bar)
{
    const int blk  = blockIdx.x;
    const int b    = blk >> 3;           // image
    const int s    = blk & (SPB - 1);    // strip
    const int tid  = threadIdx.x;
    const int wave = tid >> 6;
    const int lane = tid & 63;
    const int r0   = s * BROWS + wave * WROWS;
    const int colo = lane * PX;
    const size_t base = (size_t)b * NPIX;

    __shared__ _Float16 seam[4][2][W];   // [wave][0=row0 | 1=row31] raw fp16
    __shared__ float  smax[4];
    __shared__ float  smin[4];
    __shared__ double ssum[4];

    half8_t fld[2 * WROWS];              // this thread's raw field patch

    float prev[PX], cur[PX], nxt[PX];
    float m, mn;
    double sum;

    auto do_row = [&](int i) {
        float L = __shfl_up(cur[PX - 1], 1, 64);
        float R = __shfl_down(cur[0], 1, 64);
        if (lane == 0)  L = 0.f;         // image left edge
        if (lane == 63) R = 0.f;         // image right edge
        half8_t o0, o1;
        float rs = 0.f;
        #pragma unroll
        for (int j = 0; j < PX; ++j) {
            float lf = j ? cur[j - 1] : L;
            float rf = (j < PX - 1) ? cur[j + 1] : R;
            float e  = fmaxf(0.2f * (cur[j] + lf + rf + prev[j] + nxt[j]) - 0.5f, 0.f);
            if (j < 8) o0[j] = (_Float16)e; else o1[j - 8] = (_Float16)e;
            m = fmaxf(m, e); mn = fminf(mn, e); rs += e;
        }
        sum += (double)rs;
        fld[2 * i] = o0; fld[2 * i + 1] = o1;
        #pragma unroll
        for (int j = 0; j < PX; ++j) { prev[j] = cur[j]; cur[j] = nxt[j]; }
    };

    // ================= iteration 0: bound on the fly (fp32) -> y_0 in fld =================
    {
        Raw A, B;
        const bool topin = (r0 > 0);
        if (topin) load_raw(pred, target, base + (size_t)(r0 - 1) * W + colo, A);
        load_raw(pred, target, base + (size_t)r0 * W + colo, B);
        bound_from(A, prev, topin);
        bound_from(B, cur, true);
        load_raw(pred, target, base + (size_t)(r0 + 1) * W + colo, A);  // r0+1 < H always
        m = 0.f; mn = __uint_as_float(0x7f800000u); sum = 0.0;
        #pragma unroll
        for (int i = 0; i < WROWS; i += 2) {
            // even step: A = raw row r0+i+1 (in-bounds); prefetch B = row r0+i+2
            {
                const int rB = r0 + i + 2;
                const bool inbB = rB < H;
                if (inbB) load_raw(pred, target, base + (size_t)rB * W + colo, B);
                bound_from(A, nxt, true);
                do_row(i);
            }
            // odd step: B = raw row r0+i+2 (maybe OOB); prefetch A = row r0+i+3
            {
                const bool inbB = (r0 + i + 2) < H;
                if (i + 2 < WROWS)
                    load_raw(pred, target, base + (size_t)(r0 + i + 3) * W + colo, A);
                bound_from(B, nxt, inbB);
                do_row(i + 1);
            }
        }
    }

    // ================= iterations: stats -> barrier -> normalize+conv in regs =================
    for (int k = 0; k < ITERS; ++k) {
        // publish block-boundary rows of y_k for neighbor blocks (parity k&1)
        if (k < ITERS - 1) {
            if (wave == 0) {
                _Float16* hp = halo + halo_off(k & 1, b, s, 0) + colo;
                *(half8_t*)hp = fld[0];
                *(half8_t*)(hp + 8) = fld[1];
            } else if (wave == 3) {
                _Float16* hp = halo + halo_off(k & 1, b, s, 1) + colo;
                *(half8_t*)hp = fld[2 * WROWS - 2];
                *(half8_t*)(hp + 8) = fld[2 * WROWS - 1];
            }
        }
        // block stats of y_k -> one atomic set per block
        {
            float rm = m, rn = mn; double rs = sum;
            #pragma unroll
            for (int off = 32; off > 0; off >>= 1) {
                rm = fmaxf(rm, __shfl_down(rm, off, 64));
                rn = fminf(rn, __shfl_down(rn, off, 64));
                rs += __shfl_down(rs, off, 64);
            }
            if (lane == 0) { smax[wave] = rm; smin[wave] = rn; ssum[wave] = rs; }
            __syncthreads();
            if (tid == 0) {
                rm = fmaxf(fmaxf(smax[0], smax[1]), fmaxf(smax[2], smax[3]));
                rn = fminf(fminf(smin[0], smin[1]), fminf(smin[2], smin[3]));
                rs = ssum[0] + ssum[1] + ssum[2] + ssum[3];
                atomicMax(&st->maxbits[k][b], __float_as_uint(rm));
                atomicMin(&st->minbits[k][b], __float_as_uint(rn));
                atomicAdd(&st->sum[k][b], rs);
            }
        }
        if (k == ITERS - 1) break;
        grid_barrier(bar, k);

        float emax = __uint_as_float(__hip_atomic_load(&st->maxbits[k][b],
                        __ATOMIC_RELAXED, __HIP_MEMORY_SCOPE_AGENT));
        float emn  = __uint_as_float(__hip_atomic_load(&st->minbits[k][b],
                        __ATOMIC_RELAXED, __HIP_MEMORY_SCOPE_AGENT));
        float denom = emax - emn;
        float emin = 0.f, invd = 1.f;
        if (denom != 0.f) { emin = emn; invd = 1.f / denom; }
        // else: identity -> erosion kept raw, matching reference

        // intra-block wave-seam exchange of OLD boundary rows via LDS
        {
            _Float16* sp0 = &seam[wave][0][colo];
            *(half8_t*)sp0 = fld[0];
            *(half8_t*)(sp0 + 8) = fld[1];
            _Float16* sp1 = &seam[wave][1][colo];
            *(half8_t*)sp1 = fld[2 * WROWS - 2];
            *(half8_t*)(sp1 + 8) = fld[2 * WROWS - 1];
        }
        __syncthreads();

        half8_t ta0 = {}, ta1 = {}, tb0 = {}, tb1 = {};
        bool topz = false, botz = false;
        if (wave > 0) {
            const _Float16* p = &seam[wave - 1][1][colo];
            ta0 = *(const half8_t*)p; ta1 = *(const half8_t*)(p + 8);
        } else if (s > 0) {
            const _Float16* p = halo + halo_off(k & 1, b, s - 1, 1) + colo;
            ta0 = *(const half8_t*)p; ta1 = *(const half8_t*)(p + 8);
        } else topz = true;              // image top: zero padding
        if (wave < 3) {
            const _Float16* p = &seam[wave + 1][0][colo];
            tb0 = *(const half8_t*)p; tb1 = *(const half8_t*)(p + 8);
        } else if (s < SPB - 1) {
            const _Float16* p = halo + halo_off(k & 1, b, s + 1, 0) + colo;
            tb0 = *(const half8_t*)p; tb1 = *(const half8_t*)(p + 8);
        } else botz = true;              // image bottom: zero padding

        // sliding-window update, all in registers
        if (topz) {
            #pragma unroll
            for (int j = 0; j < PX; ++j) prev[j] = 0.f;
        } else norm_pair(prev, ta0, ta1, emin, invd);
        norm_pair(cur, fld[0], fld[1], emin, invd);
        m = 0.f; mn = __uint_as_float(0x7f800000u); sum = 0.0;
        #pragma unroll
        for (int i = 0; i < WROWS; ++i) {
            if (i < WROWS - 1) {
                norm_pair(nxt, fld[2 * i + 2], fld[2 * i + 3], emin, invd);
            } else if (botz) {
                #pragma unroll
                for (int j = 0; j < PX; ++j) nxt[j] = 0.f;
            } else {
                norm_pair(nxt, tb0, tb1, emin, invd);
            }
            do_row(i);
        }
    }
}

// loss = (1/(B*N)) * sum_k (k+1)^2 * [ (sum_raw - N*emin)/denom  if denom != 0 else sum_raw ]
__global__ void finalize(const Stats* __restrict__ st, float* __restrict__ out) {
    if (threadIdx.x == 0 && blockIdx.x == 0) {
        double total = 0.0;
        for (int k = 0; k < ITERS; ++k) {
            double w = (double)((k + 1) * (k + 1));
            for (int b = 0; b < BATCH; ++b) {
                float emax  = __uint_as_float(st->maxbits[k][b]);
                float emn   = __uint_as_float(st->minbits[k][b]);
                float denom = emax - emn;
                double ssv = st->sum[k][b];
                double sn;
                if (denom != 0.f)
                    sn = (ssv - (double)NPIX * (double)emn) / (double)denom;
                else
                    sn = ssv;
                total += w * sn;
            }
        }
        out[0] = (float)(total / ((double)BATCH * (double)NPIX));
    }
}

extern "C" void kernel_launch(void* const* d_in, const int* in_sizes, int n_in,
                              void* d_out, int out_size, void* d_ws, size_t ws_size,
                              hipStream_t stream) {
    (void)in_sizes; (void)n_in; (void)out_size; (void)ws_size;
    const float* pred   = (const float*)d_in[0];
    const int*   target = (const int*)d_in[1];

    char* ws = (char*)d_ws;
    Stats*    st   = (Stats*)ws;                 // ~5 KB
    unsigned* bar  = (unsigned*)(ws + 8192);
    _Float16* halo = (_Float16*)(ws + 65536);    // 2*32*8*2*1024 halfs = 2 MB

    init_all<<<2, 256, 0, stream>>>(st, bar);
    erode_persist<<<NBLK, 256, 0, stream>>>(pred, target, halo, st, bar);
    finalize<<<1, 64, 0, stream>>>(st, (float*)d_out);
}

// Round 9
// 1146.050 us; speedup vs baseline: 1.1491x; 1.1491x over previous
//
#include <hip/hip_runtime.h>

#define BATCH 32
#define H 1024
#define W 1024
#define NPIX (H * W)       // 1048576 per sample
#define ITERS 10
#define SPB 8              // strips (blocks) per image
#define NBLK (BATCH * SPB) // 256 blocks = 1 per CU (co-resident: NBLK <= #CUs, 147KB LDS forces 1/CU)
#define PROWS (H / SPB)    // 128 rows per block
#define WR 32              // rows per wave (wave = full 1024-px row, 16 px/lane)
#define LROWS 16           // first 16 rows of each wave span live in LDS
#define VROWS 16           // last 16 rows live in VGPRs (32 x half8 = 128 VGPRs)
#define PX 16              // px per lane per row

typedef _Float16 half8_t __attribute__((ext_vector_type(8)));

// Per-(iteration, batch) reduction state.
struct Stats {
    unsigned maxbits[ITERS][BATCH];  // fp32 bits; values >= 0 so uint order == float order
    unsigned minbits[ITERS][BATCH];
    double   sum[ITERS][BATCH];
};

__global__ void init_all(Stats* st, unsigned* bar) {
    int i = blockIdx.x * blockDim.x + threadIdx.x;
    if (i < ITERS * BATCH) {
        (&st->maxbits[0][0])[i] = 0u;           // erosion >= 0 everywhere
        (&st->minbits[0][0])[i] = 0x7f800000u;  // +inf
        (&st->sum[0][0])[i]     = 0.0;
    }
    if (i == 0) *bar = 0u;                      // grid-barrier epoch counter
}

// halo layout: [parity][b][s][side][W] raw fp16; side 0 = block top row, 1 = bottom row
__device__ __forceinline__ size_t halo_off(int parity, int b, int s, int side) {
    return ((((size_t)parity * BATCH + b) * SPB + s) * 2 + side) * W;
}

// bound = (pred-(target==0))^2 for 16 px, fp16-rounded (to match the packed
// interior field exactly), returned as f32.
__device__ __forceinline__ void bound_row16(const float* __restrict__ pred,
                                            const int* __restrict__ tgt,
                                            size_t off, float f[PX]) {
    #pragma unroll
    for (int q = 0; q < 4; ++q) {
        float4 p = *(const float4*)(pred + off + 4 * q);
        int4   t = *(const int4*)(tgt + off + 4 * q);
        float d;
        d = p.x - (t.x == 0 ? 1.f : 0.f); f[4*q+0] = (float)(_Float16)(d * d);
        d = p.y - (t.y == 0 ? 1.f : 0.f); f[4*q+1] = (float)(_Float16)(d * d);
        d = p.z - (t.z == 0 ? 1.f : 0.f); f[4*q+2] = (float)(_Float16)(d * d);
        d = p.w - (t.w == 0 ? 1.f : 0.f); f[4*q+3] = (float)(_Float16)(d * d);
    }
}

__device__ __forceinline__ void cvt16(float f[PX], half8_t a, half8_t b) {
    #pragma unroll
    for (int j = 0; j < 8; ++j) { f[j] = (float)a[j]; f[j + 8] = (float)b[j]; }
}

__device__ __forceinline__ void set16(float f[PX], float v) {
    #pragma unroll
    for (int j = 0; j < PX; ++j) f[j] = v;
}

__device__ __forceinline__ void pack16(const float f[PX], half8_t& o0, half8_t& o1) {
    #pragma unroll
    for (int j = 0; j < 8; ++j) { o0[j] = (_Float16)f[j]; o1[j] = (_Float16)f[j + 8]; }
}

// Block stats tail: wave reduce -> LDS -> one atomic set per block (proven R3-R8).
__device__ __forceinline__ void block_stats(float m, float mn, double sum,
                                            Stats* __restrict__ st, int iter, int b) {
    const int tid = threadIdx.x;
    const int lane = tid & 63, wave = tid >> 6;
    #pragma unroll
    for (int off = 32; off > 0; off >>= 1) {
        m   = fmaxf(m,  __shfl_down(m,  off, 64));
        mn  = fminf(mn, __shfl_down(mn, off, 64));
        sum += __shfl_down(sum, off, 64);
    }
    __shared__ float  smax[4];
    __shared__ float  smin[4];
    __shared__ double ssum[4];
    if (lane == 0) { smax[wave] = m; smin[wave] = mn; ssum[wave] = sum; }
    __syncthreads();
    if (tid == 0) {
        m   = fmaxf(fmaxf(smax[0], smax[1]), fmaxf(smax[2], smax[3]));
        mn  = fminf(fminf(smin[0], smin[1]), fminf(smin[2], smin[3]));
        sum = ssum[0] + ssum[1] + ssum[2] + ssum[3];
        atomicMax(&st->maxbits[iter][b], __float_as_uint(m));
        atomicMin(&st->minbits[iter][b], __float_as_uint(mn));
        atomicAdd(&st->sum[iter][b], sum);
    }
}

// Epoch-based grid barrier (proven R6/R8). Counter reset by init_all each launch.
__device__ __forceinline__ void grid_barrier(unsigned* bar, int epoch) {
    __threadfence();
    __syncthreads();
    if (threadIdx.x == 0) {
        atomicAdd(bar, 1u);
        unsigned tgt = (unsigned)NBLK * (unsigned)(epoch + 1);
        while (__hip_atomic_load(bar, __ATOMIC_RELAXED, __HIP_MEMORY_SCOPE_AGENT) < tgt) {
            __builtin_amdgcn_s_sleep(2);
        }
    }
    __syncthreads();
    __threadfence();
}

// Persistent kernel: erosion field resident in LDS (rows 0-15 of each wave
// span) + VGPRs (rows 16-31). All 10 iterations run here; only boundary rows
// travel through a 16KB LDS seam (wave seams) and a 2MB parity halo (block
// seams). Normalization is folded into the conv affine:
//   e = max(S5 * (0.2/d) - (mn/d + 0.5), 0), padding taps = raw mn.
__global__ __launch_bounds__(256, 1) void erode_persist(
    const float* __restrict__ pred, const int* __restrict__ target,
    _Float16* __restrict__ halo, Stats* __restrict__ st, unsigned* __restrict__ bar)
{
    const int blk  = blockIdx.x;
    const int b    = blk >> 3;           // image
    const int s    = blk & (SPB - 1);    // strip
    const int tid  = threadIdx.x;
    const int wave = tid >> 6;
    const int lane = tid & 63;
    const int colo = lane * PX;
    const int gr0  = s * PROWS + wave * WR;   // global first row of this wave's span
    const size_t base = (size_t)b * NPIX;

    __shared__ _Float16 lfld[4][LROWS][W];    // 128 KB field (LDS half)
    __shared__ _Float16 sm[4][2][W];          // 16 KB old-boundary seam

    half8_t vf[2 * VROWS];                    // field rows 16..31 (128 VGPRs)

    float prev[PX], cur[PX], nxt[PX];
    float m, mn;
    double sum;
    float scale, shiftc, eminv;

    // ================= load phase: field := fp16(bound) =================
    {
        const size_t rbase = base + (size_t)gr0 * W + colo;
        float f[PX];
        #pragma unroll
        for (int r = 0; r < LROWS; ++r) {
            bound_row16(pred, target, rbase + (size_t)r * W, f);
            half8_t o0, o1; pack16(f, o0, o1);
            *(half8_t*)&lfld[wave][r][colo] = o0;
            *(half8_t*)&lfld[wave][r][colo + 8] = o1;
        }
        #pragma unroll
        for (int r = 0; r < VROWS; ++r) {
            bound_row16(pred, target, rbase + (size_t)(LROWS + r) * W, f);
            pack16(f, vf[2 * r], vf[2 * r + 1]);
        }
    }

    auto do_row = [&](half8_t& o0, half8_t& o1) {
        float L = __shfl_up(cur[PX - 1], 1, 64);
        float R = __shfl_down(cur[0], 1, 64);
        if (lane == 0)  L = eminv;           // image left edge (raw padding = emin)
        if (lane == 63) R = eminv;           // image right edge
        float rs = 0.f;
        #pragma unroll
        for (int j = 0; j < PX; ++j) {
            float lf = j ? cur[j - 1] : L;
            float rf = (j < PX - 1) ? cur[j + 1] : R;
            float S  = cur[j] + lf + rf + prev[j] + nxt[j];
            float e  = fmaxf(fmaf(S, scale, -shiftc), 0.f);
            if (j < 8) o0[j] = (_Float16)e; else o1[j - 8] = (_Float16)e;
            m = fmaxf(m, e); mn = fminf(mn, e); rs += e;
        }
        sum += (double)rs;
        #pragma unroll
        for (int j = 0; j < PX; ++j) { prev[j] = cur[j]; cur[j] = nxt[j]; }
    };

    // ================= iterations k = 0..9 =================
    for (int k = 0; k < ITERS; ++k) {
        if (k > 0) grid_barrier(bar, k - 1);

        scale = 0.2f; shiftc = 0.5f; eminv = 0.f;   // k==0 / denom==0: identity
        if (k > 0) {
            float emax = __uint_as_float(__hip_atomic_load(&st->maxbits[k-1][b],
                            __ATOMIC_RELAXED, __HIP_MEMORY_SCOPE_AGENT));
            float emn  = __uint_as_float(__hip_atomic_load(&st->minbits[k-1][b],
                            __ATOMIC_RELAXED, __HIP_MEMORY_SCOPE_AGENT));
            float denom = emax - emn;
            if (denom != 0.f) {
                float invd = 1.f / denom;
                scale = 0.2f * invd; shiftc = emn * invd + 0.5f; eminv = emn;
            }
        }

        // seam copies of OLD field boundary rows (own rows only), then sync
        {
            half8_t a = *(const half8_t*)&lfld[wave][0][colo];
            half8_t c = *(const half8_t*)&lfld[wave][0][colo + 8];
            *(half8_t*)&sm[wave][0][colo] = a;
            *(half8_t*)&sm[wave][0][colo + 8] = c;
            *(half8_t*)&sm[wave][1][colo]     = vf[2 * VROWS - 2];
            *(half8_t*)&sm[wave][1][colo + 8] = vf[2 * VROWS - 1];
        }
        __syncthreads();

        // prev = old row gr0-1 (raw f32)
        if (wave == 0) {
            if (s == 0) set16(prev, eminv);                       // image top
            else if (k == 0)
                bound_row16(pred, target, base + (size_t)(gr0 - 1) * W + colo, prev);
            else {
                const _Float16* p = halo + halo_off((k - 1) & 1, b, s - 1, 1) + colo;
                cvt16(prev, *(const half8_t*)p, *(const half8_t*)(p + 8));
            }
        } else {
            cvt16(prev, *(const half8_t*)&sm[wave - 1][1][colo],
                        *(const half8_t*)&sm[wave - 1][1][colo + 8]);
        }
        cvt16(cur, *(const half8_t*)&lfld[wave][0][colo],
                   *(const half8_t*)&lfld[wave][0][colo + 8]);

        m = 0.f; mn = __uint_as_float(0x7f800000u); sum = 0.0;

        // rows 0..14 (LDS half; in-place: old row r+1 read before new row r write)
        #pragma unroll
        for (int r = 0; r < LROWS - 1; ++r) {
            cvt16(nxt, *(const half8_t*)&lfld[wave][r + 1][colo],
                       *(const half8_t*)&lfld[wave][r + 1][colo + 8]);
            half8_t o0, o1; do_row(o0, o1);
            *(half8_t*)&lfld[wave][r][colo] = o0;
            *(half8_t*)&lfld[wave][r][colo + 8] = o1;
            if (r == 0 && wave == 0 && k < ITERS - 1) {
                _Float16* hp = halo + halo_off(k & 1, b, s, 0) + colo;
                *(half8_t*)hp = o0; *(half8_t*)(hp + 8) = o1;
            }
        }
        // row 15: nxt = VGPR row 16
        {
            cvt16(nxt, vf[0], vf[1]);
            half8_t o0, o1; do_row(o0, o1);
            *(half8_t*)&lfld[wave][LROWS - 1][colo] = o0;
            *(half8_t*)&lfld[wave][LROWS - 1][colo + 8] = o1;
        }
        // rows 16..30 (VGPR half)
        #pragma unroll
        for (int i = 0; i < VROWS - 1; ++i) {
            cvt16(nxt, vf[2 * i + 2], vf[2 * i + 3]);
            half8_t o0, o1; do_row(o0, o1);
            vf[2 * i] = o0; vf[2 * i + 1] = o1;
        }
        // row 31: nxt = next wave's old row0 (seam) / neighbor block / padding
        {
            if (wave < 3) {
                cvt16(nxt, *(const half8_t*)&sm[wave + 1][0][colo],
                           *(const half8_t*)&sm[wave + 1][0][colo + 8]);
            } else if (s < SPB - 1) {
                if (k == 0)
                    bound_row16(pred, target, base + (size_t)(gr0 + WR) * W + colo, nxt);
                else {
                    const _Float16* p = halo + halo_off((k - 1) & 1, b, s + 1, 0) + colo;
                    cvt16(nxt, *(const half8_t*)p, *(const half8_t*)(p + 8));
                }
            } else set16(nxt, eminv);                              // image bottom
            half8_t o0, o1; do_row(o0, o1);
            vf[2 * VROWS - 2] = o0; vf[2 * VROWS - 1] = o1;
            if (wave == 3 && k < ITERS - 1) {
                _Float16* hp = halo + halo_off(k & 1, b, s, 1) + colo;
                *(half8_t*)hp = o0; *(half8_t*)(hp + 8) = o1;
            }
        }

        block_stats(m, mn, sum, st, k, b);
    }
}

// loss = (1/(B*N)) * sum_k (k+1)^2 * [ (sum_raw - N*emin)/denom  if denom != 0 else sum_raw ]
__global__ void finalize(const Stats* __restrict__ st, float* __restrict__ out) {
    if (threadIdx.x == 0 && blockIdx.x == 0) {
        double total = 0.0;
        for (int k = 0; k < ITERS; ++k) {
            double w = (double)((k + 1) * (k + 1));
            for (int b = 0; b < BATCH; ++b) {
                float emax  = __uint_as_float(st->maxbits[k][b]);
                float emn   = __uint_as_float(st->minbits[k][b]);
                float denom = emax - emn;
                double ssv = st->sum[k][b];
                double sn;
                if (denom != 0.f)
                    sn = (ssv - (double)NPIX * (double)emn) / (double)denom;
                else
                    sn = ssv;
                total += w * sn;
            }
        }
        out[0] = (float)(total / ((double)BATCH * (double)NPIX));
    }
}

extern "C" void kernel_launch(void* const* d_in, const int* in_sizes, int n_in,
                              void* d_out, int out_size, void* d_ws, size_t ws_size,
                              hipStream_t stream) {
    (void)in_sizes; (void)n_in; (void)out_size; (void)ws_size;
    const float* pred   = (const float*)d_in[0];
    const int*   target = (const int*)d_in[1];

    char* ws = (char*)d_ws;
    Stats*    st   = (Stats*)ws;                 // ~5 KB
    unsigned* bar  = (unsigned*)(ws + 8192);
    _Float16* halo = (_Float16*)(ws + 65536);    // 2*32*8*2*1024 halfs = 2 MB

    init_all<<<2, 256, 0, stream>>>(st, bar);
    erode_persist<<<NBLK, 256, 0, stream>>>(pred, target, halo, st, bar);
    finalize<<<1, 64, 0, stream>>>(st, (float*)d_out);
}